// Round 1
// baseline (1092.964 us; speedup 1.0000x reference)
//
#include <hip/hip_runtime.h>
#include <hip/hip_bf16.h>

#define NE 32000
#define NNODES 1600
#define CCH 128
#define M0C 7
#define NSPH 49
#define NALLC 29
#define BASIS 512
#define DIN 768
#define HID 128
#define RESCALE_F 23.395238876342773f

__device__ __forceinline__ float bf16_to_f(unsigned short v) {
    unsigned int u = ((unsigned int)v) << 16;
    return __uint_as_float(u);
}
__device__ __forceinline__ unsigned short f_to_bf16(float f) {
    unsigned int u = __float_as_uint(f);
    unsigned int r = (u + 0x7FFFu + ((u >> 16) & 1u)) >> 16;
    return (unsigned short)r;
}
__device__ __forceinline__ float silu_f(float x) {
    return x / (1.0f + __expf(-x));
}

// ---------------- GEMM1: x = [dist | src_emb | tgt_emb] (768) @ w1 -> LN -> SiLU
// Block: 64 edges x 128 cols, 256 threads. Thread (tx=t&31, ty=t>>5):
// rows ty*8..ty*8+7, cols tx*4..tx*4+3.
__global__ __launch_bounds__(256) void gemm1_ln_silu(
    const float* __restrict__ dist,        // [NE,512]
    const int* __restrict__ edge_index,    // [2,NE]
    const int* __restrict__ atomic_numbers,// [NNODES]
    const float* __restrict__ src_table,   // [90,128]
    const float* __restrict__ tgt_table,   // [90,128]
    const float* __restrict__ w1,          // [768,128]
    const float* __restrict__ b1,
    const float* __restrict__ g1,
    const float* __restrict__ be1,
    float* __restrict__ H1)                // [NE,128]
{
    __shared__ float As[64][33];
    __shared__ float Bs[32][128];
    __shared__ int sidx[64];
    __shared__ int tidx[64];

    const int t = threadIdx.x;
    const int e0 = blockIdx.x * 64;
    if (t < 64) {
        sidx[t] = atomic_numbers[edge_index[e0 + t]];
    } else if (t < 128) {
        tidx[t - 64] = atomic_numbers[edge_index[NE + e0 + (t - 64)]];
    }
    __syncthreads();

    const int tx = t & 31, ty = t >> 5;
    float acc[8][4];
#pragma unroll
    for (int i = 0; i < 8; ++i)
#pragma unroll
        for (int j = 0; j < 4; ++j) acc[i][j] = 0.0f;

    const int rr = t >> 5;   // 0..7
    const int cc = t & 31;   // 0..31

    for (int kt = 0; kt < DIN / 32; ++kt) {
        const int k0 = kt * 32;
        // ---- load A tile 64x32 (8 rows per pass, 8 passes)
        if (k0 < BASIS) {
            const int k = k0 + cc;
#pragma unroll
            for (int p = 0; p < 8; ++p) {
                int r = p * 8 + rr;
                As[r][cc] = dist[(size_t)(e0 + r) * BASIS + k];
            }
        } else if (k0 < BASIS + HID) {
            const int kc = k0 + cc - BASIS;
#pragma unroll
            for (int p = 0; p < 8; ++p) {
                int r = p * 8 + rr;
                As[r][cc] = src_table[sidx[r] * HID + kc];
            }
        } else {
            const int kc = k0 + cc - (BASIS + HID);
#pragma unroll
            for (int p = 0; p < 8; ++p) {
                int r = p * 8 + rr;
                As[r][cc] = tgt_table[tidx[r] * HID + kc];
            }
        }
        // ---- load B tile 32x128
#pragma unroll
        for (int p = 0; p < 16; ++p) {
            int idx = p * 256 + t;
            int r = idx >> 7, c2 = idx & 127;
            Bs[r][c2] = w1[(size_t)(k0 + r) * HID + c2];
        }
        __syncthreads();
#pragma unroll
        for (int kk = 0; kk < 32; ++kk) {
            float4 b4 = *(const float4*)&Bs[kk][tx * 4];
#pragma unroll
            for (int i = 0; i < 8; ++i) {
                float a = As[ty * 8 + i][kk];
                acc[i][0] = fmaf(a, b4.x, acc[i][0]);
                acc[i][1] = fmaf(a, b4.y, acc[i][1]);
                acc[i][2] = fmaf(a, b4.z, acc[i][2]);
                acc[i][3] = fmaf(a, b4.w, acc[i][3]);
            }
        }
        __syncthreads();
    }

    // ---- epilogue: +b1, LayerNorm over 128 (32 lanes x 4), *g1+be1, SiLU
    const float4 bv  = *(const float4*)&b1[tx * 4];
    const float4 gv  = *(const float4*)&g1[tx * 4];
    const float4 bev = *(const float4*)&be1[tx * 4];
#pragma unroll
    for (int i = 0; i < 8; ++i) {
        float v0 = acc[i][0] + bv.x;
        float v1 = acc[i][1] + bv.y;
        float v2 = acc[i][2] + bv.z;
        float v3 = acc[i][3] + bv.w;
        float s  = v0 + v1 + v2 + v3;
        float s2 = v0 * v0 + v1 * v1 + v2 * v2 + v3 * v3;
#pragma unroll
        for (int off = 16; off > 0; off >>= 1) {
            s  += __shfl_xor(s, off, 32);
            s2 += __shfl_xor(s2, off, 32);
        }
        float mean = s * (1.0f / 128.0f);
        float var  = s2 * (1.0f / 128.0f) - mean * mean;
        float rstd = rsqrtf(var + 1e-5f);
        float o0 = silu_f((v0 - mean) * rstd * gv.x + bev.x);
        float o1 = silu_f((v1 - mean) * rstd * gv.y + bev.y);
        float o2 = silu_f((v2 - mean) * rstd * gv.z + bev.z);
        float o3 = silu_f((v3 - mean) * rstd * gv.w + bev.w);
        int e = e0 + ty * 8 + i;
        *(float4*)&H1[(size_t)e * HID + tx * 4] = make_float4(o0, o1, o2, o3);
    }
}

// ---------------- GEMM2: H1 @ w2 -> LN -> SiLU  (K=128)
__global__ __launch_bounds__(256) void gemm2_ln_silu(
    const float* __restrict__ H1,  // [NE,128]
    const float* __restrict__ w2,  // [128,128]
    const float* __restrict__ b2,
    const float* __restrict__ g2,
    const float* __restrict__ be2,
    float* __restrict__ H2)        // [NE,128]
{
    __shared__ float As[64][33];
    __shared__ float Bs[32][128];

    const int t = threadIdx.x;
    const int e0 = blockIdx.x * 64;
    const int tx = t & 31, ty = t >> 5;
    float acc[8][4];
#pragma unroll
    for (int i = 0; i < 8; ++i)
#pragma unroll
        for (int j = 0; j < 4; ++j) acc[i][j] = 0.0f;

    const int rr = t >> 5, cc = t & 31;

    for (int kt = 0; kt < HID / 32; ++kt) {
        const int k0 = kt * 32;
#pragma unroll
        for (int p = 0; p < 8; ++p) {
            int r = p * 8 + rr;
            As[r][cc] = H1[(size_t)(e0 + r) * HID + k0 + cc];
        }
#pragma unroll
        for (int p = 0; p < 16; ++p) {
            int idx = p * 256 + t;
            int r = idx >> 7, c2 = idx & 127;
            Bs[r][c2] = w2[(size_t)(k0 + r) * HID + c2];
        }
        __syncthreads();
#pragma unroll
        for (int kk = 0; kk < 32; ++kk) {
            float4 b4 = *(const float4*)&Bs[kk][tx * 4];
#pragma unroll
            for (int i = 0; i < 8; ++i) {
                float a = As[ty * 8 + i][kk];
                acc[i][0] = fmaf(a, b4.x, acc[i][0]);
                acc[i][1] = fmaf(a, b4.y, acc[i][1]);
                acc[i][2] = fmaf(a, b4.z, acc[i][2]);
                acc[i][3] = fmaf(a, b4.w, acc[i][3]);
            }
        }
        __syncthreads();
    }

    const float4 bv  = *(const float4*)&b2[tx * 4];
    const float4 gv  = *(const float4*)&g2[tx * 4];
    const float4 bev = *(const float4*)&be2[tx * 4];
#pragma unroll
    for (int i = 0; i < 8; ++i) {
        float v0 = acc[i][0] + bv.x;
        float v1 = acc[i][1] + bv.y;
        float v2 = acc[i][2] + bv.z;
        float v3 = acc[i][3] + bv.w;
        float s  = v0 + v1 + v2 + v3;
        float s2 = v0 * v0 + v1 * v1 + v2 * v2 + v3 * v3;
#pragma unroll
        for (int off = 16; off > 0; off >>= 1) {
            s  += __shfl_xor(s, off, 32);
            s2 += __shfl_xor(s2, off, 32);
        }
        float mean = s * (1.0f / 128.0f);
        float var  = s2 * (1.0f / 128.0f) - mean * mean;
        float rstd = rsqrtf(var + 1e-5f);
        float o0 = silu_f((v0 - mean) * rstd * gv.x + bev.x);
        float o1 = silu_f((v1 - mean) * rstd * gv.y + bev.y);
        float o2 = silu_f((v2 - mean) * rstd * gv.z + bev.z);
        float o3 = silu_f((v3 - mean) * rstd * gv.w + bev.w);
        int e = e0 + ty * 8 + i;
        *(float4*)&H2[(size_t)e * HID + tx * 4] = make_float4(o0, o1, o2, o3);
    }
}

// ---------------- GEMM3: H2 @ w3 + b3, scaled by 1/RESCALE, bf16 out. N=896 tiled by 128.
__global__ __launch_bounds__(256) void gemm3_x0(
    const float* __restrict__ H2,   // [NE,128]
    const float* __restrict__ w3,   // [128,896]
    const float* __restrict__ b3,   // [896]
    unsigned short* __restrict__ X0)// [NE,896] bf16
{
    __shared__ float As[64][33];
    __shared__ float Bs[32][128];

    const int t = threadIdx.x;
    const int e0 = blockIdx.x * 64;
    const int n0 = blockIdx.y * 128;
    const int tx = t & 31, ty = t >> 5;
    float acc[8][4];
#pragma unroll
    for (int i = 0; i < 8; ++i)
#pragma unroll
        for (int j = 0; j < 4; ++j) acc[i][j] = 0.0f;

    const int rr = t >> 5, cc = t & 31;

    for (int kt = 0; kt < HID / 32; ++kt) {
        const int k0 = kt * 32;
#pragma unroll
        for (int p = 0; p < 8; ++p) {
            int r = p * 8 + rr;
            As[r][cc] = H2[(size_t)(e0 + r) * HID + k0 + cc];
        }
#pragma unroll
        for (int p = 0; p < 16; ++p) {
            int idx = p * 256 + t;
            int r = idx >> 7, c2 = idx & 127;
            Bs[r][c2] = w3[(size_t)(k0 + r) * 896 + n0 + c2];
        }
        __syncthreads();
#pragma unroll
        for (int kk = 0; kk < 32; ++kk) {
            float4 b4 = *(const float4*)&Bs[kk][tx * 4];
#pragma unroll
            for (int i = 0; i < 8; ++i) {
                float a = As[ty * 8 + i][kk];
                acc[i][0] = fmaf(a, b4.x, acc[i][0]);
                acc[i][1] = fmaf(a, b4.y, acc[i][1]);
                acc[i][2] = fmaf(a, b4.z, acc[i][2]);
                acc[i][3] = fmaf(a, b4.w, acc[i][3]);
            }
        }
        __syncthreads();
    }

    const float4 bv = *(const float4*)&b3[n0 + tx * 4];
    const float inv_res = 1.0f / RESCALE_F;
#pragma unroll
    for (int i = 0; i < 8; ++i) {
        int e = e0 + ty * 8 + i;
        ushort4 u;
        u.x = f_to_bf16((acc[i][0] + bv.x) * inv_res);
        u.y = f_to_bf16((acc[i][1] + bv.y) * inv_res);
        u.z = f_to_bf16((acc[i][2] + bv.z) * inv_res);
        u.w = f_to_bf16((acc[i][3] + bv.w) * inv_res);
        *(ushort4*)&X0[(size_t)e * 896 + n0 + tx * 4] = u;
    }
}

// ---------------- rotate (49x7 selected wigner cols @ 7x128 x0) + atomic scatter
__global__ __launch_bounds__(256) void rotate_scatter(
    const unsigned short* __restrict__ X0, // [NE,7,128] bf16 (already /RESCALE)
    const float* __restrict__ wig,         // [NE,49,29]
    const int* __restrict__ edge_index,    // [2,NE]
    float* __restrict__ out)               // [1600,49,128]
{
    __shared__ float Xs[M0C][CCH];
    __shared__ float Ws[NSPH][8];

    const int e = blockIdx.x;
    const int t = threadIdx.x;

    // load x0 (bf16 -> f32), 896 elems via 448 dword loads
    const unsigned int* x0v = (const unsigned int*)(X0 + (size_t)e * 896);
    for (int idx = t; idx < 448; idx += 256) {
        unsigned int u = x0v[idx];
        int b0 = idx * 2;
        Xs[b0 >> 7][b0 & 127] = bf16_to_f((unsigned short)(u & 0xFFFFu));
        int b1i = b0 + 1;
        Xs[b1i >> 7][b1i & 127] = bf16_to_f((unsigned short)(u >> 16));
    }
    // load selected wigner columns: cols {0,2,6,11,16,21,26}
    const float* wbase = wig + (size_t)e * (NSPH * NALLC);
    for (int idx = t; idx < NSPH * 8; idx += 256) {
        int i = idx >> 3, o = idx & 7;
        if (o < 7) {
            int col = (o < 2) ? (2 * o) : (5 * o - 4);
            Ws[i][o] = wbase[i * NALLC + col];
        }
    }
    __syncthreads();

    const int tn = edge_index[NE + e];
    float* outp = out + (size_t)tn * (NSPH * CCH);
    const int c = t & 127;
    for (int i = t >> 7; i < NSPH; i += 2) {
        float v = 0.0f;
#pragma unroll
        for (int o = 0; o < 7; ++o) v = fmaf(Ws[i][o], Xs[o][c], v);
        atomicAdd(&outp[i * CCH + c], v);
    }
}

extern "C" void kernel_launch(void* const* d_in, const int* in_sizes, int n_in,
                              void* d_out, int out_size, void* d_ws, size_t ws_size,
                              hipStream_t stream) {
    const int*   atomic_numbers = (const int*)d_in[0];
    const float* edge_distance  = (const float*)d_in[1];
    const int*   edge_index     = (const int*)d_in[2];
    const float* src_table      = (const float*)d_in[3];
    const float* tgt_table      = (const float*)d_in[4];
    const float* w1  = (const float*)d_in[5];
    const float* b1  = (const float*)d_in[6];
    const float* g1  = (const float*)d_in[7];
    const float* be1 = (const float*)d_in[8];
    const float* w2  = (const float*)d_in[9];
    const float* b2  = (const float*)d_in[10];
    const float* g2  = (const float*)d_in[11];
    const float* be2 = (const float*)d_in[12];
    const float* w3  = (const float*)d_in[13];
    const float* b3  = (const float*)d_in[14];
    // d_in[15] = to_m (fixed permutation, hard-coded)
    const float* wig = (const float*)d_in[16];

    float* H1 = (float*)d_ws;                      // NE*128 f32 = 16.4 MB
    float* H2 = H1 + (size_t)NE * HID;             // NE*128 f32 = 16.4 MB
    unsigned short* X0 = (unsigned short*)(H2 + (size_t)NE * HID); // NE*896 bf16 = 57.3 MB

    hipMemsetAsync(d_out, 0, (size_t)out_size * sizeof(float), stream);

    gemm1_ln_silu<<<NE / 64, 256, 0, stream>>>(
        edge_distance, edge_index, atomic_numbers, src_table, tgt_table,
        w1, b1, g1, be1, H1);
    gemm2_ln_silu<<<NE / 64, 256, 0, stream>>>(H1, w2, b2, g2, be2, H2);
    gemm3_x0<<<dim3(NE / 64, 7), 256, 0, stream>>>(H2, w3, b3, X0);
    rotate_scatter<<<NE, 256, 0, stream>>>(X0, wig, edge_index, (float*)d_out);
}

// Round 2
// 650.311 us; speedup vs baseline: 1.6807x; 1.6807x over previous
//
#include <hip/hip_runtime.h>
#include <hip/hip_bf16.h>

#define NE 32000
#define NNODES 1600
#define CCH 128
#define M0C 7
#define NSPH 49
#define NALLC 29
#define BASIS 512
#define DIN 768
#define HID 128
#define RESCALE_F 23.395238876342773f

__device__ __forceinline__ float bf16_to_f(unsigned short v) {
    unsigned int u = ((unsigned int)v) << 16;
    return __uint_as_float(u);
}
__device__ __forceinline__ unsigned short f_to_bf16(float f) {
    unsigned int u = __float_as_uint(f);
    unsigned int r = (u + 0x7FFFu + ((u >> 16) & 1u)) >> 16;
    return (unsigned short)r;
}
__device__ __forceinline__ float silu_f(float x) {
    return x / (1.0f + __expf(-x));
}

// ---------------- GEMM1: x = [dist | src_emb | tgt_emb] (768) @ w1 -> LN -> SiLU
__global__ __launch_bounds__(256) void gemm1_ln_silu(
    const float* __restrict__ dist,        // [NE,512]
    const int* __restrict__ edge_index,    // [2,NE]
    const int* __restrict__ atomic_numbers,// [NNODES]
    const float* __restrict__ src_table,   // [90,128]
    const float* __restrict__ tgt_table,   // [90,128]
    const float* __restrict__ w1,          // [768,128]
    const float* __restrict__ b1,
    const float* __restrict__ g1,
    const float* __restrict__ be1,
    float* __restrict__ H1)                // [NE,128]
{
    __shared__ float As[64][33];
    __shared__ float Bs[32][128];
    __shared__ int sidx[64];
    __shared__ int tidx[64];

    const int t = threadIdx.x;
    const int e0 = blockIdx.x * 64;
    if (t < 64) {
        sidx[t] = atomic_numbers[edge_index[e0 + t]];
    } else if (t < 128) {
        tidx[t - 64] = atomic_numbers[edge_index[NE + e0 + (t - 64)]];
    }
    __syncthreads();

    const int tx = t & 31, ty = t >> 5;
    float acc[8][4];
#pragma unroll
    for (int i = 0; i < 8; ++i)
#pragma unroll
        for (int j = 0; j < 4; ++j) acc[i][j] = 0.0f;

    const int rr = t >> 5;   // 0..7
    const int cc = t & 31;   // 0..31

    for (int kt = 0; kt < DIN / 32; ++kt) {
        const int k0 = kt * 32;
        if (k0 < BASIS) {
            const int k = k0 + cc;
#pragma unroll
            for (int p = 0; p < 8; ++p) {
                int r = p * 8 + rr;
                As[r][cc] = dist[(size_t)(e0 + r) * BASIS + k];
            }
        } else if (k0 < BASIS + HID) {
            const int kc = k0 + cc - BASIS;
#pragma unroll
            for (int p = 0; p < 8; ++p) {
                int r = p * 8 + rr;
                As[r][cc] = src_table[sidx[r] * HID + kc];
            }
        } else {
            const int kc = k0 + cc - (BASIS + HID);
#pragma unroll
            for (int p = 0; p < 8; ++p) {
                int r = p * 8 + rr;
                As[r][cc] = tgt_table[tidx[r] * HID + kc];
            }
        }
#pragma unroll
        for (int p = 0; p < 16; ++p) {
            int idx = p * 256 + t;
            int r = idx >> 7, c2 = idx & 127;
            Bs[r][c2] = w1[(size_t)(k0 + r) * HID + c2];
        }
        __syncthreads();
#pragma unroll
        for (int kk = 0; kk < 32; ++kk) {
            float4 b4 = *(const float4*)&Bs[kk][tx * 4];
#pragma unroll
            for (int i = 0; i < 8; ++i) {
                float a = As[ty * 8 + i][kk];
                acc[i][0] = fmaf(a, b4.x, acc[i][0]);
                acc[i][1] = fmaf(a, b4.y, acc[i][1]);
                acc[i][2] = fmaf(a, b4.z, acc[i][2]);
                acc[i][3] = fmaf(a, b4.w, acc[i][3]);
            }
        }
        __syncthreads();
    }

    const float4 bv  = *(const float4*)&b1[tx * 4];
    const float4 gv  = *(const float4*)&g1[tx * 4];
    const float4 bev = *(const float4*)&be1[tx * 4];
#pragma unroll
    for (int i = 0; i < 8; ++i) {
        float v0 = acc[i][0] + bv.x;
        float v1 = acc[i][1] + bv.y;
        float v2 = acc[i][2] + bv.z;
        float v3 = acc[i][3] + bv.w;
        float s  = v0 + v1 + v2 + v3;
        float s2 = v0 * v0 + v1 * v1 + v2 * v2 + v3 * v3;
#pragma unroll
        for (int off = 16; off > 0; off >>= 1) {
            s  += __shfl_xor(s, off, 32);
            s2 += __shfl_xor(s2, off, 32);
        }
        float mean = s * (1.0f / 128.0f);
        float var  = s2 * (1.0f / 128.0f) - mean * mean;
        float rstd = rsqrtf(var + 1e-5f);
        float o0 = silu_f((v0 - mean) * rstd * gv.x + bev.x);
        float o1 = silu_f((v1 - mean) * rstd * gv.y + bev.y);
        float o2 = silu_f((v2 - mean) * rstd * gv.z + bev.z);
        float o3 = silu_f((v3 - mean) * rstd * gv.w + bev.w);
        int e = e0 + ty * 8 + i;
        *(float4*)&H1[(size_t)e * HID + tx * 4] = make_float4(o0, o1, o2, o3);
    }
}

// ---------------- GEMM2: H1 @ w2 -> LN -> SiLU  (K=128)
__global__ __launch_bounds__(256) void gemm2_ln_silu(
    const float* __restrict__ H1,  // [NE,128]
    const float* __restrict__ w2,  // [128,128]
    const float* __restrict__ b2,
    const float* __restrict__ g2,
    const float* __restrict__ be2,
    float* __restrict__ H2)        // [NE,128]
{
    __shared__ float As[64][33];
    __shared__ float Bs[32][128];

    const int t = threadIdx.x;
    const int e0 = blockIdx.x * 64;
    const int tx = t & 31, ty = t >> 5;
    float acc[8][4];
#pragma unroll
    for (int i = 0; i < 8; ++i)
#pragma unroll
        for (int j = 0; j < 4; ++j) acc[i][j] = 0.0f;

    const int rr = t >> 5, cc = t & 31;

    for (int kt = 0; kt < HID / 32; ++kt) {
        const int k0 = kt * 32;
#pragma unroll
        for (int p = 0; p < 8; ++p) {
            int r = p * 8 + rr;
            As[r][cc] = H1[(size_t)(e0 + r) * HID + k0 + cc];
        }
#pragma unroll
        for (int p = 0; p < 16; ++p) {
            int idx = p * 256 + t;
            int r = idx >> 7, c2 = idx & 127;
            Bs[r][c2] = w2[(size_t)(k0 + r) * HID + c2];
        }
        __syncthreads();
#pragma unroll
        for (int kk = 0; kk < 32; ++kk) {
            float4 b4 = *(const float4*)&Bs[kk][tx * 4];
#pragma unroll
            for (int i = 0; i < 8; ++i) {
                float a = As[ty * 8 + i][kk];
                acc[i][0] = fmaf(a, b4.x, acc[i][0]);
                acc[i][1] = fmaf(a, b4.y, acc[i][1]);
                acc[i][2] = fmaf(a, b4.z, acc[i][2]);
                acc[i][3] = fmaf(a, b4.w, acc[i][3]);
            }
        }
        __syncthreads();
    }

    const float4 bv  = *(const float4*)&b2[tx * 4];
    const float4 gv  = *(const float4*)&g2[tx * 4];
    const float4 bev = *(const float4*)&be2[tx * 4];
#pragma unroll
    for (int i = 0; i < 8; ++i) {
        float v0 = acc[i][0] + bv.x;
        float v1 = acc[i][1] + bv.y;
        float v2 = acc[i][2] + bv.z;
        float v3 = acc[i][3] + bv.w;
        float s  = v0 + v1 + v2 + v3;
        float s2 = v0 * v0 + v1 * v1 + v2 * v2 + v3 * v3;
#pragma unroll
        for (int off = 16; off > 0; off >>= 1) {
            s  += __shfl_xor(s, off, 32);
            s2 += __shfl_xor(s2, off, 32);
        }
        float mean = s * (1.0f / 128.0f);
        float var  = s2 * (1.0f / 128.0f) - mean * mean;
        float rstd = rsqrtf(var + 1e-5f);
        float o0 = silu_f((v0 - mean) * rstd * gv.x + bev.x);
        float o1 = silu_f((v1 - mean) * rstd * gv.y + bev.y);
        float o2 = silu_f((v2 - mean) * rstd * gv.z + bev.z);
        float o3 = silu_f((v3 - mean) * rstd * gv.w + bev.w);
        int e = e0 + ty * 8 + i;
        *(float4*)&H2[(size_t)e * HID + tx * 4] = make_float4(o0, o1, o2, o3);
    }
}

// ---------------- GEMM3: H2 @ w3 + b3, scaled by 1/RESCALE, bf16 out. N=896 tiled by 128.
__global__ __launch_bounds__(256) void gemm3_x0(
    const float* __restrict__ H2,   // [NE,128]
    const float* __restrict__ w3,   // [128,896]
    const float* __restrict__ b3,   // [896]
    unsigned short* __restrict__ X0)// [NE,896] bf16
{
    __shared__ float As[64][33];
    __shared__ float Bs[32][128];

    const int t = threadIdx.x;
    const int e0 = blockIdx.x * 64;
    const int n0 = blockIdx.y * 128;
    const int tx = t & 31, ty = t >> 5;
    float acc[8][4];
#pragma unroll
    for (int i = 0; i < 8; ++i)
#pragma unroll
        for (int j = 0; j < 4; ++j) acc[i][j] = 0.0f;

    const int rr = t >> 5, cc = t & 31;

    for (int kt = 0; kt < HID / 32; ++kt) {
        const int k0 = kt * 32;
#pragma unroll
        for (int p = 0; p < 8; ++p) {
            int r = p * 8 + rr;
            As[r][cc] = H2[(size_t)(e0 + r) * HID + k0 + cc];
        }
#pragma unroll
        for (int p = 0; p < 16; ++p) {
            int idx = p * 256 + t;
            int r = idx >> 7, c2 = idx & 127;
            Bs[r][c2] = w3[(size_t)(k0 + r) * 896 + n0 + c2];
        }
        __syncthreads();
#pragma unroll
        for (int kk = 0; kk < 32; ++kk) {
            float4 b4 = *(const float4*)&Bs[kk][tx * 4];
#pragma unroll
            for (int i = 0; i < 8; ++i) {
                float a = As[ty * 8 + i][kk];
                acc[i][0] = fmaf(a, b4.x, acc[i][0]);
                acc[i][1] = fmaf(a, b4.y, acc[i][1]);
                acc[i][2] = fmaf(a, b4.z, acc[i][2]);
                acc[i][3] = fmaf(a, b4.w, acc[i][3]);
            }
        }
        __syncthreads();
    }

    const float4 bv = *(const float4*)&b3[n0 + tx * 4];
    const float inv_res = 1.0f / RESCALE_F;
#pragma unroll
    for (int i = 0; i < 8; ++i) {
        int e = e0 + ty * 8 + i;
        ushort4 u;
        u.x = f_to_bf16((acc[i][0] + bv.x) * inv_res);
        u.y = f_to_bf16((acc[i][1] + bv.y) * inv_res);
        u.z = f_to_bf16((acc[i][2] + bv.z) * inv_res);
        u.w = f_to_bf16((acc[i][3] + bv.w) * inv_res);
        *(ushort4*)&X0[(size_t)e * 896 + n0 + tx * 4] = u;
    }
}

// ---------------- bucket building: counting sort of edges by target node
__global__ __launch_bounds__(256) void hist_kernel(
    const int* __restrict__ edge_index, int* __restrict__ cnt)
{
    int e = blockIdx.x * 256 + threadIdx.x;
    if (e < NE) atomicAdd(&cnt[edge_index[NE + e]], 1);
}

__global__ __launch_bounds__(256) void scan_kernel(
    const int* __restrict__ cnt, int* __restrict__ offs, int* __restrict__ cur)
{
    __shared__ int part[256];
    const int t = threadIdx.x;
    const int base = t * 7;   // 256*7 = 1792 >= 1600
    int s = 0;
#pragma unroll
    for (int j = 0; j < 7; ++j) {
        int i = base + j;
        if (i < NNODES) s += cnt[i];
    }
    part[t] = s;
    __syncthreads();
    for (int off = 1; off < 256; off <<= 1) {
        int v = (t >= off) ? part[t - off] : 0;
        __syncthreads();
        part[t] += v;
        __syncthreads();
    }
    int run = (t > 0) ? part[t - 1] : 0;
#pragma unroll
    for (int j = 0; j < 7; ++j) {
        int i = base + j;
        if (i < NNODES) {
            offs[i] = run;
            cur[i] = run;
            run += cnt[i];
        }
    }
    if (t == 0) offs[NNODES] = part[255];
}

__global__ __launch_bounds__(256) void scatter_kernel(
    const int* __restrict__ edge_index, int* __restrict__ cur, int* __restrict__ order)
{
    int e = blockIdx.x * 256 + threadIdx.x;
    if (e < NE) {
        int tgt = edge_index[NE + e];
        int pos = atomicAdd(&cur[tgt], 1);
        order[pos] = e;
    }
}

// ---------------- rotate + gather-reduce: one block per target node, no atomics
__global__ __launch_bounds__(256) void rotate_gather(
    const unsigned short* __restrict__ X0, // [NE,7,128] bf16 (already /RESCALE)
    const float* __restrict__ wig,         // [NE,49,29]
    const int* __restrict__ order,         // [NE] edge ids sorted by target
    const int* __restrict__ offs,          // [NNODES+1]
    float* __restrict__ out)               // [1600,49,128]
{
    __shared__ float Xs[M0C][CCH];   // 7 x 128
    __shared__ float Ws[NSPH][8];    // 49 x 7 (padded to 8)

    const int node = blockIdx.x;
    const int t = threadIdx.x;
    const int cg = t & 31;   // cols 4*cg .. 4*cg+3
    const int rg = t >> 5;   // rows rg, rg+8, rg+16, ...
    const int beg = offs[node], end = offs[node + 1];

    float acc[7][4];
#pragma unroll
    for (int r = 0; r < 7; ++r)
#pragma unroll
        for (int j = 0; j < 4; ++j) acc[r][j] = 0.0f;

    for (int k = beg; k < end; ++k) {
        const int e = order[k];
        // stage x0[e] (bf16 -> f32): 448 dwords
        const unsigned int* xv = (const unsigned int*)(X0 + (size_t)e * 896);
        for (int idx = t; idx < 448; idx += 256) {
            unsigned int u = xv[idx];
            int b0 = idx * 2;
            Xs[b0 >> 7][b0 & 127]       = bf16_to_f((unsigned short)(u & 0xFFFFu));
            Xs[b0 >> 7][(b0 & 127) + 1] = bf16_to_f((unsigned short)(u >> 16));
        }
        // stage selected wigner cols {0,2,6,11,16,21,26}
        const float* wb = wig + (size_t)e * (NSPH * NALLC);
        for (int idx = t; idx < NSPH * 8; idx += 256) {
            int i = idx >> 3, o = idx & 7;
            float v = 0.0f;
            if (o < 7) {
                int col = (o < 2) ? (2 * o) : (5 * o - 4);
                v = wb[i * NALLC + col];
            }
            Ws[i][o] = v;
        }
        __syncthreads();

        float4 xr[7];
#pragma unroll
        for (int o = 0; o < 7; ++o) xr[o] = *(const float4*)&Xs[o][cg * 4];

#pragma unroll
        for (int r = 0; r < 7; ++r) {
            int i = rg + 8 * r;
            if (i < NSPH) {
                float4 wa = *(const float4*)&Ws[i][0];
                float4 wc = *(const float4*)&Ws[i][4];
                float w[7] = {wa.x, wa.y, wa.z, wa.w, wc.x, wc.y, wc.z};
#pragma unroll
                for (int o = 0; o < 7; ++o) {
                    acc[r][0] = fmaf(w[o], xr[o].x, acc[r][0]);
                    acc[r][1] = fmaf(w[o], xr[o].y, acc[r][1]);
                    acc[r][2] = fmaf(w[o], xr[o].z, acc[r][2]);
                    acc[r][3] = fmaf(w[o], xr[o].w, acc[r][3]);
                }
            }
        }
        __syncthreads();
    }

    float* op = out + (size_t)node * (NSPH * CCH);
#pragma unroll
    for (int r = 0; r < 7; ++r) {
        int i = rg + 8 * r;
        if (i < NSPH) {
            *(float4*)&op[i * CCH + cg * 4] =
                make_float4(acc[r][0], acc[r][1], acc[r][2], acc[r][3]);
        }
    }
}

extern "C" void kernel_launch(void* const* d_in, const int* in_sizes, int n_in,
                              void* d_out, int out_size, void* d_ws, size_t ws_size,
                              hipStream_t stream) {
    const int*   atomic_numbers = (const int*)d_in[0];
    const float* edge_distance  = (const float*)d_in[1];
    const int*   edge_index     = (const int*)d_in[2];
    const float* src_table      = (const float*)d_in[3];
    const float* tgt_table      = (const float*)d_in[4];
    const float* w1  = (const float*)d_in[5];
    const float* b1  = (const float*)d_in[6];
    const float* g1  = (const float*)d_in[7];
    const float* be1 = (const float*)d_in[8];
    const float* w2  = (const float*)d_in[9];
    const float* b2  = (const float*)d_in[10];
    const float* g2  = (const float*)d_in[11];
    const float* be2 = (const float*)d_in[12];
    const float* w3  = (const float*)d_in[13];
    const float* b3  = (const float*)d_in[14];
    // d_in[15] = to_m (fixed permutation, hard-coded)
    const float* wig = (const float*)d_in[16];

    float* H1 = (float*)d_ws;                      // NE*128 f32 = 16.4 MB
    float* H2 = H1 + (size_t)NE * HID;             // NE*128 f32 = 16.4 MB
    unsigned short* X0 = (unsigned short*)(H2 + (size_t)NE * HID); // NE*896 bf16 = 57.3 MB

    // bucket arrays alias H1's space: H1 is dead after gemm2, and bucket
    // kernels launch after gemm3. (cnt/offs/cur/order = 36801 ints << 16 MB)
    int* cnt   = (int*)H1;
    int* offs  = cnt + NNODES;          // NNODES+1
    int* cur   = offs + NNODES + 1;
    int* order = cur + NNODES;          // NE

    gemm1_ln_silu<<<NE / 64, 256, 0, stream>>>(
        edge_distance, edge_index, atomic_numbers, src_table, tgt_table,
        w1, b1, g1, be1, H1);
    gemm2_ln_silu<<<NE / 64, 256, 0, stream>>>(H1, w2, b2, g2, be2, H2);
    gemm3_x0<<<dim3(NE / 64, 7), 256, 0, stream>>>(H2, w3, b3, X0);

    hipMemsetAsync(cnt, 0, NNODES * sizeof(int), stream);
    hist_kernel<<<(NE + 255) / 256, 256, 0, stream>>>(edge_index, cnt);
    scan_kernel<<<1, 256, 0, stream>>>(cnt, offs, cur);
    scatter_kernel<<<(NE + 255) / 256, 256, 0, stream>>>(edge_index, cur, order);
    rotate_gather<<<NNODES, 256, 0, stream>>>(X0, wig, order, offs, (float*)d_out);
}

// Round 3
// 620.951 us; speedup vs baseline: 1.7601x; 1.0473x over previous
//
#include <hip/hip_runtime.h>
#include <hip/hip_bf16.h>

#define NE 32000
#define NNODES 1600
#define CCH 128
#define M0C 7
#define NSPH 49
#define NALLC 29
#define BASIS 512
#define DIN 768
#define HID 128
#define RESCALE_F 23.395238876342773f

typedef __bf16 bf16x8 __attribute__((ext_vector_type(8)));
typedef float  f32x4  __attribute__((ext_vector_type(4)));

__device__ __forceinline__ float bf16_to_f(unsigned short v) {
    unsigned int u = ((unsigned int)v) << 16;
    return __uint_as_float(u);
}
__device__ __forceinline__ unsigned short f_to_bf16(float f) {
    unsigned int u = __float_as_uint(f);
    unsigned int r = (u + 0x7FFFu + ((u >> 16) & 1u)) >> 16;
    return (unsigned short)r;
}
__device__ __forceinline__ float silu_f(float x) {
    return x / (1.0f + __expf(-x));
}

// ---------------- prepack X = [dist | src_emb | tgt_emb] -> bf16 [NE,768]
__global__ __launch_bounds__(256) void prepack_x(
    const float* __restrict__ dist,
    const int* __restrict__ edge_index,
    const int* __restrict__ atomic_numbers,
    const float* __restrict__ src_table,
    const float* __restrict__ tgt_table,
    unsigned short* __restrict__ Xb)
{
    int idx = blockIdx.x * 256 + threadIdx.x;   // NE*192 float4-slots
    if (idx >= NE * 192) return;
    int e = idx / 192;
    int q = idx - e * 192;
    float4 v;
    int dst;
    if (q < 128) {
        v = ((const float4*)dist)[(size_t)e * 128 + q];
        dst = q * 4;
    } else if (q < 160) {
        int s = atomic_numbers[edge_index[e]];
        v = ((const float4*)src_table)[s * 32 + (q - 128)];
        dst = 512 + (q - 128) * 4;
    } else {
        int s = atomic_numbers[edge_index[NE + e]];
        v = ((const float4*)tgt_table)[s * 32 + (q - 160)];
        dst = 640 + (q - 160) * 4;
    }
    ushort4 u;
    u.x = f_to_bf16(v.x); u.y = f_to_bf16(v.y);
    u.z = f_to_bf16(v.z); u.w = f_to_bf16(v.w);
    *(ushort4*)&Xb[(size_t)e * 768 + dst] = u;
}

// ---------------- prepack weights: transpose to n-major, convert to bf16
__global__ __launch_bounds__(256) void prepack_w(
    const float* __restrict__ w1, const float* __restrict__ w2, const float* __restrict__ w3,
    unsigned short* __restrict__ w1t,  // [128][768]
    unsigned short* __restrict__ w2t,  // [128][128]
    unsigned short* __restrict__ w3t)  // [896][128]
{
    int idx = blockIdx.x * 256 + threadIdx.x;
    if (idx < 98304) {                       // 128*768
        int n = idx / 768, k = idx - n * 768;
        w1t[idx] = f_to_bf16(w1[(size_t)k * 128 + n]);
    } else if (idx < 114688) {               // + 128*128
        int j = idx - 98304;
        int n = j / 128, k = j - n * 128;
        w2t[j] = f_to_bf16(w2[(size_t)k * 128 + n]);
    } else if (idx < 229376) {               // + 896*128
        int j = idx - 114688;
        int n = j / 128, k = j - n * 128;
        w3t[j] = f_to_bf16(w3[(size_t)k * 896 + n]);
    }
}

// ---------------- MFMA GEMM + LN + SiLU (generic over K), 64 rows/block, 4 waves x 16 rows
// A: [M,K] bf16 row-major; Bt: [128,K] bf16 (n-major); out bf16 [M,128].
template<int K>
__global__ __launch_bounds__(256) void gemm_ln_mfma(
    const unsigned short* __restrict__ A,
    const unsigned short* __restrict__ Bt,
    const float* __restrict__ bias,
    const float* __restrict__ gam,
    const float* __restrict__ bet,
    unsigned short* __restrict__ Out)
{
    const int t = threadIdx.x;
    const int wv = t >> 6, lane = t & 63;
    const int m = lane & 15, quad = lane >> 4;
    const int row0 = blockIdx.x * 64 + wv * 16;

    f32x4 acc[8] = {};
    const unsigned short* arow = A + (size_t)(row0 + m) * K + quad * 8;
    const unsigned short* bb   = Bt + (size_t)m * K + quad * 8;

#pragma unroll 2
    for (int k0 = 0; k0 < K; k0 += 32) {
        bf16x8 af = *(const bf16x8*)(arow + k0);
#pragma unroll
        for (int ct = 0; ct < 8; ++ct) {
            bf16x8 bfv = *(const bf16x8*)(bb + (size_t)ct * 16 * K + k0);
            acc[ct] = __builtin_amdgcn_mfma_f32_16x16x32_bf16(af, bfv, acc[ct], 0, 0, 0);
        }
    }

    float bbv[8], ggv[8], eev[8];
#pragma unroll
    for (int ct = 0; ct < 8; ++ct) {
        bbv[ct] = bias[ct * 16 + m];
        ggv[ct] = gam[ct * 16 + m];
        eev[ct] = bet[ct * 16 + m];
    }
#pragma unroll
    for (int reg = 0; reg < 4; ++reg) {
        float v[8];
        float s = 0.f, s2 = 0.f;
#pragma unroll
        for (int ct = 0; ct < 8; ++ct) {
            v[ct] = acc[ct][reg] + bbv[ct];
            s += v[ct]; s2 += v[ct] * v[ct];
        }
#pragma unroll
        for (int off = 1; off < 16; off <<= 1) {
            s  += __shfl_xor(s, off, 64);
            s2 += __shfl_xor(s2, off, 64);
        }
        float mean = s * (1.0f / 128.0f);
        float var  = s2 * (1.0f / 128.0f) - mean * mean;
        float rstd = rsqrtf(var + 1e-5f);
        int row = row0 + 4 * quad + reg;
#pragma unroll
        for (int ct = 0; ct < 8; ++ct) {
            float o = silu_f((v[ct] - mean) * rstd * ggv[ct] + eev[ct]);
            Out[(size_t)row * 128 + ct * 16 + m] = f_to_bf16(o);
        }
    }
}

// ---------------- GEMM3: H2b @ w3t + b3, /RESCALE -> bf16 X0 [NE,896]
__global__ __launch_bounds__(256) void gemm3_mfma(
    const unsigned short* __restrict__ A,    // [NE,128]
    const unsigned short* __restrict__ w3t,  // [896,128]
    const float* __restrict__ b3,            // [896]
    unsigned short* __restrict__ X0)         // [NE,896]
{
    const int t = threadIdx.x;
    const int wv = t >> 6, lane = t & 63;
    const int m = lane & 15, quad = lane >> 4;
    const int row0 = blockIdx.x * 64 + wv * 16;
    const int nb0 = blockIdx.y * 128;

    f32x4 acc[8] = {};
    const unsigned short* arow = A + (size_t)(row0 + m) * 128 + quad * 8;
    const unsigned short* bb   = w3t + (size_t)(nb0 + m) * 128 + quad * 8;

#pragma unroll
    for (int k0 = 0; k0 < 128; k0 += 32) {
        bf16x8 af = *(const bf16x8*)(arow + k0);
#pragma unroll
        for (int ct = 0; ct < 8; ++ct) {
            bf16x8 bfv = *(const bf16x8*)(bb + (size_t)ct * 16 * 128 + k0);
            acc[ct] = __builtin_amdgcn_mfma_f32_16x16x32_bf16(af, bfv, acc[ct], 0, 0, 0);
        }
    }

    const float inv_res = 1.0f / RESCALE_F;
#pragma unroll
    for (int reg = 0; reg < 4; ++reg) {
        int row = row0 + 4 * quad + reg;
#pragma unroll
        for (int ct = 0; ct < 8; ++ct) {
            int col = nb0 + ct * 16 + m;
            float o = (acc[ct][reg] + b3[col]) * inv_res;
            X0[(size_t)row * 896 + col] = f_to_bf16(o);
        }
    }
}

// ---------------- bucket building: counting sort of edges by target node
__global__ __launch_bounds__(256) void hist_kernel(
    const int* __restrict__ edge_index, int* __restrict__ cnt)
{
    int e = blockIdx.x * 256 + threadIdx.x;
    if (e < NE) atomicAdd(&cnt[edge_index[NE + e]], 1);
}

__global__ __launch_bounds__(256) void scan_kernel(
    const int* __restrict__ cnt, int* __restrict__ offs, int* __restrict__ cur)
{
    __shared__ int part[256];
    const int t = threadIdx.x;
    const int base = t * 7;
    int s = 0;
#pragma unroll
    for (int j = 0; j < 7; ++j) {
        int i = base + j;
        if (i < NNODES) s += cnt[i];
    }
    part[t] = s;
    __syncthreads();
    for (int off = 1; off < 256; off <<= 1) {
        int v = (t >= off) ? part[t - off] : 0;
        __syncthreads();
        part[t] += v;
        __syncthreads();
    }
    int run = (t > 0) ? part[t - 1] : 0;
#pragma unroll
    for (int j = 0; j < 7; ++j) {
        int i = base + j;
        if (i < NNODES) {
            offs[i] = run;
            cur[i] = run;
            run += cnt[i];
        }
    }
    if (t == 0) offs[NNODES] = part[255];
}

__global__ __launch_bounds__(256) void scatter_kernel(
    const int* __restrict__ edge_index, int* __restrict__ cur, int* __restrict__ order)
{
    int e = blockIdx.x * 256 + threadIdx.x;
    if (e < NE) {
        int tgt = edge_index[NE + e];
        int pos = atomicAdd(&cur[tgt], 1);
        order[pos] = e;
    }
}

// ---------------- rotate + gather-reduce: one block per node, 4 edges per round
#define EB 4
__global__ __launch_bounds__(256) void rotate_gather(
    const unsigned short* __restrict__ X0, // [NE,7,128] bf16 (already /RESCALE)
    const float* __restrict__ wig,         // [NE,49,29]
    const int* __restrict__ order,         // [NE] edge ids sorted by target
    const int* __restrict__ offs,          // [NNODES+1]
    float* __restrict__ out)               // [1600,49,128]
{
    __shared__ float Xs[EB][M0C][CCH];   // 4 x 7 x 128
    __shared__ float Ws[EB][NSPH][8];    // 4 x 49 x 8

    const int node = blockIdx.x;
    const int t = threadIdx.x;
    const int cg = t & 31;   // cols 4*cg .. 4*cg+3
    const int rg = t >> 5;   // rows rg, rg+8, ...
    const int beg = offs[node], end = offs[node + 1];

    float acc[7][4];
#pragma unroll
    for (int r = 0; r < 7; ++r)
#pragma unroll
        for (int j = 0; j < 4; ++j) acc[r][j] = 0.0f;

    for (int k = beg; k < end; k += EB) {
        const int nb = min(EB, end - k);
        // stage X0 for nb edges: nb*448 dwords
        for (int idx = t; idx < nb * 448; idx += 256) {
            int b = idx / 448, r = idx - b * 448;
            const unsigned int* xv =
                (const unsigned int*)(X0 + (size_t)order[k + b] * 896);
            unsigned int u = xv[r];
            int b0 = r * 2;
            Xs[b][b0 >> 7][b0 & 127]       = bf16_to_f((unsigned short)(u & 0xFFFFu));
            Xs[b][b0 >> 7][(b0 & 127) + 1] = bf16_to_f((unsigned short)(u >> 16));
        }
        // stage selected wigner cols {0,2,6,11,16,21,26} for nb edges
        for (int idx = t; idx < nb * 392; idx += 256) {
            int b = idx / 392, r = idx - b * 392;
            int i = r >> 3, o = r & 7;
            if (o < 7) {
                int col = (o < 2) ? (2 * o) : (5 * o - 4);
                Ws[b][i][o] =
                    wig[(size_t)order[k + b] * (NSPH * NALLC) + i * NALLC + col];
            }
        }
        __syncthreads();

#pragma unroll
        for (int b = 0; b < EB; ++b) {
            if (b < nb) {
                float4 xr[7];
#pragma unroll
                for (int o = 0; o < 7; ++o) xr[o] = *(const float4*)&Xs[b][o][cg * 4];
#pragma unroll
                for (int r = 0; r < 7; ++r) {
                    int i = rg + 8 * r;
                    if (i < NSPH) {
                        float4 wa = *(const float4*)&Ws[b][i][0];
                        float4 wc = *(const float4*)&Ws[b][i][4];
                        float w[7] = {wa.x, wa.y, wa.z, wa.w, wc.x, wc.y, wc.z};
#pragma unroll
                        for (int o = 0; o < 7; ++o) {
                            acc[r][0] = fmaf(w[o], xr[o].x, acc[r][0]);
                            acc[r][1] = fmaf(w[o], xr[o].y, acc[r][1]);
                            acc[r][2] = fmaf(w[o], xr[o].z, acc[r][2]);
                            acc[r][3] = fmaf(w[o], xr[o].w, acc[r][3]);
                        }
                    }
                }
            }
        }
        __syncthreads();
    }

    float* op = out + (size_t)node * (NSPH * CCH);
#pragma unroll
    for (int r = 0; r < 7; ++r) {
        int i = rg + 8 * r;
        if (i < NSPH) {
            *(float4*)&op[i * CCH + cg * 4] =
                make_float4(acc[r][0], acc[r][1], acc[r][2], acc[r][3]);
        }
    }
}

extern "C" void kernel_launch(void* const* d_in, const int* in_sizes, int n_in,
                              void* d_out, int out_size, void* d_ws, size_t ws_size,
                              hipStream_t stream) {
    const int*   atomic_numbers = (const int*)d_in[0];
    const float* edge_distance  = (const float*)d_in[1];
    const int*   edge_index     = (const int*)d_in[2];
    const float* src_table      = (const float*)d_in[3];
    const float* tgt_table      = (const float*)d_in[4];
    const float* w1  = (const float*)d_in[5];
    const float* b1  = (const float*)d_in[6];
    const float* g1  = (const float*)d_in[7];
    const float* be1 = (const float*)d_in[8];
    const float* w2  = (const float*)d_in[9];
    const float* b2  = (const float*)d_in[10];
    const float* g2  = (const float*)d_in[11];
    const float* be2 = (const float*)d_in[12];
    const float* w3  = (const float*)d_in[13];
    const float* b3  = (const float*)d_in[14];
    // d_in[15] = to_m (fixed permutation, hard-coded)
    const float* wig = (const float*)d_in[16];

    char* ws = (char*)d_ws;
    // Aliased layout (peak 66.2 MB; R1 proved ws >= 90.1 MB):
    //   Xb  [0, 49.152M)            : dead after gemm1
    //   H1b [49.152M, 57.344M)      : dead after gemm2
    //   H2b [0, 8.192M)   (over Xb) : dead after gemm3
    //   X0  [8.192M, 65.536M)  (over Xb tail + H1b, both dead by gemm3)
    //   w1t/w2t/w3t at 65.536M ; bucket ints after
    unsigned short* Xb  = (unsigned short*)(ws);
    unsigned short* H1b = (unsigned short*)(ws + 49152000);
    unsigned short* H2b = (unsigned short*)(ws);
    unsigned short* X0  = (unsigned short*)(ws + 8192000);
    unsigned short* w1t = (unsigned short*)(ws + 65536000);
    unsigned short* w2t = (unsigned short*)(ws + 65536000 + 196608);
    unsigned short* w3t = (unsigned short*)(ws + 65536000 + 196608 + 32768);
    int* cnt   = (int*)(ws + 65536000 + 196608 + 32768 + 229376);
    int* offs  = cnt + NNODES;
    int* cur   = offs + NNODES + 1;
    int* order = cur + NNODES;

    // bucket build (independent of MLP)
    hipMemsetAsync(cnt, 0, NNODES * sizeof(int), stream);
    hist_kernel<<<(NE + 255) / 256, 256, 0, stream>>>(edge_index, cnt);
    scan_kernel<<<1, 256, 0, stream>>>(cnt, offs, cur);
    scatter_kernel<<<(NE + 255) / 256, 256, 0, stream>>>(edge_index, cur, order);

    // prepack
    prepack_w<<<(229376 + 255) / 256, 256, 0, stream>>>(w1, w2, w3, w1t, w2t, w3t);
    prepack_x<<<(NE * 192 + 255) / 256, 256, 0, stream>>>(
        edge_distance, edge_index, atomic_numbers, src_table, tgt_table, Xb);

    // MLP (bf16 MFMA)
    gemm_ln_mfma<768><<<NE / 64, 256, 0, stream>>>(Xb, w1t, b1, g1, be1, H1b);
    gemm_ln_mfma<128><<<NE / 64, 256, 0, stream>>>(H1b, w2t, b2, g2, be2, H2b);
    gemm3_mfma<<<dim3(NE / 64, 7), 256, 0, stream>>>(H2b, w3t, b3, X0);

    // rotate + reduce
    rotate_gather<<<NNODES, 256, 0, stream>>>(X0, wig, order, offs, (float*)d_out);
}

// Round 4
// 608.590 us; speedup vs baseline: 1.7959x; 1.0203x over previous
//
#include <hip/hip_runtime.h>
#include <hip/hip_bf16.h>

#define NE 32000
#define NNODES 1600
#define CCH 128
#define M0C 7
#define NSPH 49
#define NALLC 29
#define BASIS 512
#define DIN 768
#define HID 128
#define RESCALE_F 23.395238876342773f
#define CH 28                      // edges per rotate chunk
#define MAXCH (NE / CH + NNODES)   // 2743 upper bound on chunk count

typedef __bf16 bf16x8 __attribute__((ext_vector_type(8)));
typedef __bf16 bf16x2 __attribute__((ext_vector_type(2)));
typedef float  f32x4  __attribute__((ext_vector_type(4)));

__device__ __forceinline__ float bf16_to_f(unsigned short v) {
    unsigned int u = ((unsigned int)v) << 16;
    return __uint_as_float(u);
}
__device__ __forceinline__ unsigned short f_to_bf16(float f) {
    unsigned int u = __float_as_uint(f);
    unsigned int r = (u + 0x7FFFu + ((u >> 16) & 1u)) >> 16;
    return (unsigned short)r;
}
__device__ __forceinline__ float silu_f(float x) {
    return x / (1.0f + __expf(-x));
}

// dot2 over a bf16 pair packed in a dword: c += lo(a)*lo(b) + hi(a)*hi(b)
__device__ __forceinline__ float dot2_bf16(unsigned int a, unsigned int b, float c) {
#if __has_builtin(__builtin_amdgcn_fdot2_f32_bf16)
    union { unsigned int u; bf16x2 h; } ua, ub;
    ua.u = a; ub.u = b;
    return __builtin_amdgcn_fdot2_f32_bf16(ua.h, ub.h, c, false);
#else
    float r = c;
    r = fmaf(__uint_as_float(a << 16), __uint_as_float(b << 16), r);
    r = fmaf(__uint_as_float(a & 0xFFFF0000u), __uint_as_float(b & 0xFFFF0000u), r);
    return r;
#endif
}

// ---------------- prepack weights: transpose to n-major, convert to bf16
__global__ __launch_bounds__(256) void prepack_w(
    const float* __restrict__ w1, const float* __restrict__ w2, const float* __restrict__ w3,
    unsigned short* __restrict__ w1t,  // [128][768]
    unsigned short* __restrict__ w2t,  // [128][128]
    unsigned short* __restrict__ w3t)  // [896][128]
{
    int idx = blockIdx.x * 256 + threadIdx.x;
    if (idx < 98304) {                       // 128*768
        int n = idx / 768, k = idx - n * 768;
        w1t[idx] = f_to_bf16(w1[(size_t)k * 128 + n]);
    } else if (idx < 114688) {               // + 128*128
        int j = idx - 98304;
        int n = j / 128, k = j - n * 128;
        w2t[j] = f_to_bf16(w2[(size_t)k * 128 + n]);
    } else if (idx < 229376) {               // + 896*128
        int j = idx - 114688;
        int n = j / 128, k = j - n * 128;
        w3t[j] = f_to_bf16(w3[(size_t)k * 896 + n]);
    }
}

// ---------------- GEMM1 fused: A = [dist|src|tgt] fp32 loaded direct, cvt in-reg.
// 64 rows/block, 4 waves x 16 rows, MFMA 16x16x32 bf16, LN+SiLU epilogue.
__global__ __launch_bounds__(256) void gemm1_ln_mfma(
    const float* __restrict__ dist,         // [NE,512]
    const int* __restrict__ edge_index,     // [2,NE]
    const int* __restrict__ atomic_numbers, // [NNODES]
    const float* __restrict__ src_table,    // [90,128]
    const float* __restrict__ tgt_table,    // [90,128]
    const unsigned short* __restrict__ w1t, // [128][768] bf16
    const float* __restrict__ bias,
    const float* __restrict__ gam,
    const float* __restrict__ bet,
    unsigned short* __restrict__ Out)       // [NE,128] bf16
{
    const int t = threadIdx.x;
    const int wv = t >> 6, lane = t & 63;
    const int m = lane & 15, quad = lane >> 4;
    const int row0 = blockIdx.x * 64 + wv * 16;
    const int row = row0 + m;

    const int sid  = atomic_numbers[edge_index[row]];
    const int tid2 = atomic_numbers[edge_index[NE + row]];
    const float* a0 = dist + (size_t)row * 512 + quad * 8;
    const float* a1 = src_table + sid * 128 + quad * 8;
    const float* a2 = tgt_table + tid2 * 128 + quad * 8;
    const unsigned short* bb = w1t + (size_t)m * 768 + quad * 8;

    f32x4 acc[8] = {};

#pragma unroll
    for (int k0 = 0; k0 < 768; k0 += 32) {
        const float* ap = (k0 < 512) ? (a0 + k0)
                        : (k0 < 640) ? (a1 + (k0 - 512))
                                     : (a2 + (k0 - 640));
        float4 va = *(const float4*)ap;
        float4 vb = *(const float4*)(ap + 4);
        bf16x8 af;
        af[0] = (__bf16)va.x; af[1] = (__bf16)va.y;
        af[2] = (__bf16)va.z; af[3] = (__bf16)va.w;
        af[4] = (__bf16)vb.x; af[5] = (__bf16)vb.y;
        af[6] = (__bf16)vb.z; af[7] = (__bf16)vb.w;
#pragma unroll
        for (int ct = 0; ct < 8; ++ct) {
            bf16x8 bfv = *(const bf16x8*)(bb + (size_t)ct * 16 * 768 + k0);
            acc[ct] = __builtin_amdgcn_mfma_f32_16x16x32_bf16(af, bfv, acc[ct], 0, 0, 0);
        }
    }

    float bbv[8], ggv[8], eev[8];
#pragma unroll
    for (int ct = 0; ct < 8; ++ct) {
        bbv[ct] = bias[ct * 16 + m];
        ggv[ct] = gam[ct * 16 + m];
        eev[ct] = bet[ct * 16 + m];
    }
#pragma unroll
    for (int reg = 0; reg < 4; ++reg) {
        float v[8];
        float s = 0.f, s2 = 0.f;
#pragma unroll
        for (int ct = 0; ct < 8; ++ct) {
            v[ct] = acc[ct][reg] + bbv[ct];
            s += v[ct]; s2 += v[ct] * v[ct];
        }
#pragma unroll
        for (int off = 1; off < 16; off <<= 1) {
            s  += __shfl_xor(s, off, 64);
            s2 += __shfl_xor(s2, off, 64);
        }
        float mean = s * (1.0f / 128.0f);
        float var  = s2 * (1.0f / 128.0f) - mean * mean;
        float rstd = rsqrtf(var + 1e-5f);
        int orow = row0 + 4 * quad + reg;
#pragma unroll
        for (int ct = 0; ct < 8; ++ct) {
            float o = silu_f((v[ct] - mean) * rstd * ggv[ct] + eev[ct]);
            Out[(size_t)orow * 128 + ct * 16 + m] = f_to_bf16(o);
        }
    }
}

// ---------------- GEMM2 (K=128): bf16 A, LN+SiLU -> bf16
__global__ __launch_bounds__(256) void gemm2_ln_mfma(
    const unsigned short* __restrict__ A,
    const unsigned short* __restrict__ Bt,
    const float* __restrict__ bias,
    const float* __restrict__ gam,
    const float* __restrict__ bet,
    unsigned short* __restrict__ Out)
{
    const int t = threadIdx.x;
    const int wv = t >> 6, lane = t & 63;
    const int m = lane & 15, quad = lane >> 4;
    const int row0 = blockIdx.x * 64 + wv * 16;

    f32x4 acc[8] = {};
    const unsigned short* arow = A + (size_t)(row0 + m) * 128 + quad * 8;
    const unsigned short* bb   = Bt + (size_t)m * 128 + quad * 8;

#pragma unroll
    for (int k0 = 0; k0 < 128; k0 += 32) {
        bf16x8 af = *(const bf16x8*)(arow + k0);
#pragma unroll
        for (int ct = 0; ct < 8; ++ct) {
            bf16x8 bfv = *(const bf16x8*)(bb + (size_t)ct * 16 * 128 + k0);
            acc[ct] = __builtin_amdgcn_mfma_f32_16x16x32_bf16(af, bfv, acc[ct], 0, 0, 0);
        }
    }

    float bbv[8], ggv[8], eev[8];
#pragma unroll
    for (int ct = 0; ct < 8; ++ct) {
        bbv[ct] = bias[ct * 16 + m];
        ggv[ct] = gam[ct * 16 + m];
        eev[ct] = bet[ct * 16 + m];
    }
#pragma unroll
    for (int reg = 0; reg < 4; ++reg) {
        float v[8];
        float s = 0.f, s2 = 0.f;
#pragma unroll
        for (int ct = 0; ct < 8; ++ct) {
            v[ct] = acc[ct][reg] + bbv[ct];
            s += v[ct]; s2 += v[ct] * v[ct];
        }
#pragma unroll
        for (int off = 1; off < 16; off <<= 1) {
            s  += __shfl_xor(s, off, 64);
            s2 += __shfl_xor(s2, off, 64);
        }
        float mean = s * (1.0f / 128.0f);
        float var  = s2 * (1.0f / 128.0f) - mean * mean;
        float rstd = rsqrtf(var + 1e-5f);
        int row = row0 + 4 * quad + reg;
#pragma unroll
        for (int ct = 0; ct < 8; ++ct) {
            float o = silu_f((v[ct] - mean) * rstd * ggv[ct] + eev[ct]);
            Out[(size_t)row * 128 + ct * 16 + m] = f_to_bf16(o);
        }
    }
}

// ---------------- GEMM3: H2b @ w3t + b3, /RESCALE -> bf16 X0 [NE,896]
__global__ __launch_bounds__(256) void gemm3_mfma(
    const unsigned short* __restrict__ A,    // [NE,128]
    const unsigned short* __restrict__ w3t,  // [896,128]
    const float* __restrict__ b3,            // [896]
    unsigned short* __restrict__ X0)         // [NE,896]
{
    const int t = threadIdx.x;
    const int wv = t >> 6, lane = t & 63;
    const int m = lane & 15, quad = lane >> 4;
    const int row0 = blockIdx.x * 64 + wv * 16;
    const int nb0 = blockIdx.y * 128;

    f32x4 acc[8] = {};
    const unsigned short* arow = A + (size_t)(row0 + m) * 128 + quad * 8;
    const unsigned short* bb   = w3t + (size_t)(nb0 + m) * 128 + quad * 8;

#pragma unroll
    for (int k0 = 0; k0 < 128; k0 += 32) {
        bf16x8 af = *(const bf16x8*)(arow + k0);
#pragma unroll
        for (int ct = 0; ct < 8; ++ct) {
            bf16x8 bfv = *(const bf16x8*)(bb + (size_t)ct * 16 * 128 + k0);
            acc[ct] = __builtin_amdgcn_mfma_f32_16x16x32_bf16(af, bfv, acc[ct], 0, 0, 0);
        }
    }

    const float inv_res = 1.0f / RESCALE_F;
#pragma unroll
    for (int reg = 0; reg < 4; ++reg) {
        int row = row0 + 4 * quad + reg;
#pragma unroll
        for (int ct = 0; ct < 8; ++ct) {
            int col = nb0 + ct * 16 + m;
            float o = (acc[ct][reg] + b3[col]) * inv_res;
            X0[(size_t)row * 896 + col] = f_to_bf16(o);
        }
    }
}

// ---------------- counting sort of edges by target node
__global__ __launch_bounds__(256) void hist_kernel(
    const int* __restrict__ edge_index, int* __restrict__ cnt)
{
    int e = blockIdx.x * 256 + threadIdx.x;
    if (e < NE) atomicAdd(&cnt[edge_index[NE + e]], 1);
}

__global__ __launch_bounds__(256) void scan_kernel(
    const int* __restrict__ cnt, int* __restrict__ offs, int* __restrict__ cur)
{
    __shared__ int part[256];
    const int t = threadIdx.x;
    const int base = t * 7;
    int s = 0;
#pragma unroll
    for (int j = 0; j < 7; ++j) {
        int i = base + j;
        if (i < NNODES) s += cnt[i];
    }
    part[t] = s;
    __syncthreads();
    for (int off = 1; off < 256; off <<= 1) {
        int v = (t >= off) ? part[t - off] : 0;
        __syncthreads();
        part[t] += v;
        __syncthreads();
    }
    int run = (t > 0) ? part[t - 1] : 0;
#pragma unroll
    for (int j = 0; j < 7; ++j) {
        int i = base + j;
        if (i < NNODES) {
            offs[i] = run;
            cur[i] = run;
            run += cnt[i];
        }
    }
    if (t == 0) offs[NNODES] = part[255];
}

__global__ __launch_bounds__(256) void scatter_kernel(
    const int* __restrict__ edge_index, int* __restrict__ cur, int* __restrict__ order)
{
    int e = blockIdx.x * 256 + threadIdx.x;
    if (e < NE) {
        int tgt = edge_index[NE + e];
        int pos = atomicAdd(&cur[tgt], 1);
        order[pos] = e;
    }
}

// ---------------- chunk list: one node per chunk, <=CH edges; multi-chunk nodes atomic
__global__ __launch_bounds__(256) void build_chunks(
    const int* __restrict__ offs, int* __restrict__ chunk_cnt,
    int* __restrict__ ch_node, int* __restrict__ ch_beg, int* __restrict__ ch_lm)
{
    int n = blockIdx.x * 256 + threadIdx.x;
    if (n >= NNODES) return;
    int b = offs[n], k = offs[n + 1] - b;
    if (k == 0) return;
    int nc = (k + CH - 1) / CH;
    int base = atomicAdd(chunk_cnt, nc);
    for (int c = 0; c < nc; ++c) {
        ch_node[base + c] = n;
        ch_beg[base + c]  = b + CH * c;
        int l = min(CH, k - CH * c);
        ch_lm[base + c] = l | ((nc > 1) ? 0x10000 : 0);
    }
}

// ---------------- rotate + reduce: one chunk (<=28 edges, one node) per block.
// LDS o-pair-packed bf16 layouts for v_dot2_f32_bf16; fixed trip counts everywhere.
__global__ __launch_bounds__(256) void rotate_chunks(
    const unsigned short* __restrict__ X0, // [NE,7,128] bf16 (already /RESCALE)
    const float* __restrict__ wig,         // [NE,49,29]
    const int* __restrict__ order,
    const int* __restrict__ chunk_cnt,
    const int* __restrict__ ch_node,
    const int* __restrict__ ch_beg,
    const int* __restrict__ ch_lm,
    float* __restrict__ out)               // [1600,49,128] (pre-zeroed)
{
    __shared__ unsigned short Xs[CH][CCH][8];   // [slot][col][o(7)+pad] 57344 B
    __shared__ unsigned short Ws[CH][NSPH][8];  // [slot][row][o(7)+pad] 21952 B

    const int b = blockIdx.x;
    if (b >= chunk_cnt[0]) return;
    const int node = ch_node[b];
    const int beg  = ch_beg[b];
    const int lm   = ch_lm[b];
    const int len  = lm & 0xFFFF;
    const int multi = lm >> 16;

    const int t = threadIdx.x;
    const int slot8 = t >> 3;    // 0..31 (28..31 idle in staging)
    const int lane8 = t & 7;

    if (slot8 < CH) {
        const int e = (slot8 < len) ? order[beg + slot8] : -1;
        // ---- stage X0[e] -> Xs[slot][col][o], transpose, raw bf16 copy
        const uint4* xsrc = (const uint4*)(X0 + (size_t)e * 896);
#pragma unroll
        for (int j = 0; j < 14; ++j) {
            int r = j * 8 + lane8;            // 0..111 (uint4 index; 8 bf16 each)
            uint4 v = make_uint4(0u, 0u, 0u, 0u);
            if (e >= 0) v = xsrc[r];
            int o = r >> 4;                   // 0..6
            int c0 = (r & 15) * 8;
            Xs[slot8][c0 + 0][o] = (unsigned short)(v.x & 0xFFFFu);
            Xs[slot8][c0 + 1][o] = (unsigned short)(v.x >> 16);
            Xs[slot8][c0 + 2][o] = (unsigned short)(v.y & 0xFFFFu);
            Xs[slot8][c0 + 3][o] = (unsigned short)(v.y >> 16);
            Xs[slot8][c0 + 4][o] = (unsigned short)(v.z & 0xFFFFu);
            Xs[slot8][c0 + 5][o] = (unsigned short)(v.z >> 16);
            Xs[slot8][c0 + 6][o] = (unsigned short)(v.w & 0xFFFFu);
            Xs[slot8][c0 + 7][o] = (unsigned short)(v.w >> 16);
        }
#pragma unroll
        for (int j = 0; j < 16; ++j)          // zero the o=7 pad (128 cols / 8 threads)
            Xs[slot8][j * 8 + lane8][7] = 0;

        // ---- stage selected wigner cols {0,2,6,11,16,21,26} -> Ws[slot][row][o] bf16
        const float* wsrc = wig + (size_t)e * (NSPH * NALLC);
#pragma unroll
        for (int j = 0; j < 49; ++j) {
            int idx = j * 8 + lane8;          // 0..391
            int i = idx >> 3, o = idx & 7;
            float v = 0.f;
            if (e >= 0 && o < 7) {
                int col = (o < 2) ? (2 * o) : (5 * o - 4);
                v = wsrc[i * NALLC + col];
            }
            Ws[slot8][i][o] = f_to_bf16(v);
        }
    }
    __syncthreads();

    const int cg = t & 31;   // cols 4*cg .. 4*cg+3
    const int rg = t >> 5;   // rows rg + 8r
    float acc[7][4];
#pragma unroll
    for (int r = 0; r < 7; ++r)
#pragma unroll
        for (int j = 0; j < 4; ++j) acc[r][j] = 0.0f;

    for (int s0 = 0; s0 < CH; s0 += 4) {
        if (s0 >= len) break;
#pragma unroll
        for (int ss = 0; ss < 4; ++ss) {
            const int s = s0 + ss;
            uint4 xq[4];
#pragma unroll
            for (int j = 0; j < 4; ++j)
                xq[j] = *(const uint4*)&Xs[s][4 * cg + j][0];
#pragma unroll
            for (int r = 0; r < 7; ++r) {
                int row = rg + 8 * r;
                if (row < NSPH) {
                    uint4 wq = *(const uint4*)&Ws[s][row][0];
#pragma unroll
                    for (int j = 0; j < 4; ++j) {
                        float a = acc[r][j];
                        a = dot2_bf16(xq[j].x, wq.x, a);
                        a = dot2_bf16(xq[j].y, wq.y, a);
                        a = dot2_bf16(xq[j].z, wq.z, a);
                        a = dot2_bf16(xq[j].w, wq.w, a);
                        acc[r][j] = a;
                    }
                }
            }
        }
    }

    float* op = out + (size_t)node * (NSPH * CCH);
    if (multi) {
#pragma unroll
        for (int r = 0; r < 7; ++r) {
            int row = rg + 8 * r;
            if (row < NSPH) {
#pragma unroll
                for (int j = 0; j < 4; ++j)
                    atomicAdd(&op[row * CCH + 4 * cg + j], acc[r][j]);
            }
        }
    } else {
#pragma unroll
        for (int r = 0; r < 7; ++r) {
            int row = rg + 8 * r;
            if (row < NSPH) {
                *(float4*)&op[row * CCH + 4 * cg] =
                    make_float4(acc[r][0], acc[r][1], acc[r][2], acc[r][3]);
            }
        }
    }
}

extern "C" void kernel_launch(void* const* d_in, const int* in_sizes, int n_in,
                              void* d_out, int out_size, void* d_ws, size_t ws_size,
                              hipStream_t stream) {
    const int*   atomic_numbers = (const int*)d_in[0];
    const float* edge_distance  = (const float*)d_in[1];
    const int*   edge_index     = (const int*)d_in[2];
    const float* src_table      = (const float*)d_in[3];
    const float* tgt_table      = (const float*)d_in[4];
    const float* w1  = (const float*)d_in[5];
    const float* b1  = (const float*)d_in[6];
    const float* g1  = (const float*)d_in[7];
    const float* be1 = (const float*)d_in[8];
    const float* w2  = (const float*)d_in[9];
    const float* b2  = (const float*)d_in[10];
    const float* g2  = (const float*)d_in[11];
    const float* be2 = (const float*)d_in[12];
    const float* w3  = (const float*)d_in[13];
    const float* b3  = (const float*)d_in[14];
    // d_in[15] = to_m (fixed permutation, hard-coded)
    const float* wig = (const float*)d_in[16];

    char* ws = (char*)d_ws;
    // Simple non-overlapping layout, total ~74.4 MB (ws >= 90.1 MB proven in R1)
    unsigned short* H1b = (unsigned short*)(ws);                 //  8.192 MB
    unsigned short* H2b = (unsigned short*)(ws + 8192000);       //  8.192 MB
    unsigned short* X0  = (unsigned short*)(ws + 16384000);      // 57.344 MB
    unsigned short* w1t = (unsigned short*)(ws + 73728000);      // 196608 B
    unsigned short* w2t = (unsigned short*)(ws + 73924608);      // 32768 B
    unsigned short* w3t = (unsigned short*)(ws + 73957376);      // 229376 B
    int* ints      = (int*)(ws + 74186752);
    int* cnt       = ints;                   // [1600]
    int* chunk_cnt = cnt + NNODES;           // [1]
    int* offs      = chunk_cnt + 1;          // [1601]
    int* cur       = offs + NNODES + 1;      // [1600]
    int* order     = cur + NNODES;           // [32000]
    int* ch_node   = order + NE;             // [MAXCH]
    int* ch_beg    = ch_node + MAXCH;        // [MAXCH]
    int* ch_lm     = ch_beg + MAXCH;         // [MAXCH]

    // zero cnt + chunk_cnt (adjacent), and the output (multi-chunk atomics + empty nodes)
    hipMemsetAsync(cnt, 0, (NNODES + 1) * sizeof(int), stream);
    hipMemsetAsync(d_out, 0, (size_t)out_size * sizeof(float), stream);

    // bucket + chunk build
    hist_kernel<<<(NE + 255) / 256, 256, 0, stream>>>(edge_index, cnt);
    scan_kernel<<<1, 256, 0, stream>>>(cnt, offs, cur);
    scatter_kernel<<<(NE + 255) / 256, 256, 0, stream>>>(edge_index, cur, order);
    build_chunks<<<(NNODES + 255) / 256, 256, 0, stream>>>(
        offs, chunk_cnt, ch_node, ch_beg, ch_lm);

    // weights prepack + MLP (bf16 MFMA)
    prepack_w<<<(229376 + 255) / 256, 256, 0, stream>>>(w1, w2, w3, w1t, w2t, w3t);
    gemm1_ln_mfma<<<NE / 64, 256, 0, stream>>>(
        edge_distance, edge_index, atomic_numbers, src_table, tgt_table,
        w1t, b1, g1, be1, H1b);
    gemm2_ln_mfma<<<NE / 64, 256, 0, stream>>>(H1b, w2t, b2, g2, be2, H2b);
    gemm3_mfma<<<dim3(NE / 64, 7), 256, 0, stream>>>(H2b, w3t, b3, X0);

    // rotate + reduce
    rotate_chunks<<<MAXCH, 256, 0, stream>>>(
        X0, wig, order, chunk_cnt, ch_node, ch_beg, ch_lm, (float*)d_out);
}